// Round 1
// baseline (598.043 us; speedup 1.0000x reference)
//
#include <hip/hip_runtime.h>
#include <hip/hip_bf16.h>
#include <math.h>

#define IN_F 128
#define OUT_F 64

// ---------- init: zero output accumulator, init segmax/denom ----------
__global__ __launch_bounds__(256) void k_init(float* __restrict__ out,
                                              unsigned* __restrict__ m_enc,
                                              float* __restrict__ sden, int n) {
    int tid = blockIdx.x * blockDim.x + threadIdx.x;
    int tot4 = n * 32;  // n*128 floats / 4
    if (tid < tot4) {
        ((float4*)out)[tid] = make_float4(0.f, 0.f, 0.f, 0.f);
    }
    if (tid < n) { m_enc[tid] = 0u; sden[tid] = 0.f; }
}

// ---------- fused dual GEMM + attention projections ----------
// block = 128 threads (2 waves). wave0 -> feat (W_gat) + el/er, wave1 -> support (W_gc)
__global__ __launch_bounds__(128) void k_gemm(const float* __restrict__ h,
                                              const float* __restrict__ Wg,
                                              const float* __restrict__ Wc,
                                              const float* __restrict__ attn_l,
                                              const float* __restrict__ attn_r,
                                              float* __restrict__ feat,
                                              float* __restrict__ support,
                                              float* __restrict__ el,
                                              float* __restrict__ er, int n) {
    __shared__ float Ws[2][IN_F * OUT_F];   // 64 KB
    __shared__ float hs[8][IN_F];           // 4 KB
    for (int i = threadIdx.x; i < IN_F * OUT_F; i += 128) {
        Ws[0][i] = Wg[i];
        Ws[1][i] = Wc[i];
    }
    __syncthreads();

    int lane = threadIdx.x & 63;
    int wv = threadIdx.x >> 6;
    int row0 = blockIdx.x * 8;
    if (row0 >= n) return;
    int nr = min(8, n - row0);

    // load 8 rows of h as float4 (contiguous)
    {
        const float4* src = (const float4*)(h + (size_t)row0 * IN_F);
        float4* dst = (float4*)hs;
        int tot = nr * (IN_F / 4);
        for (int i = threadIdx.x; i < tot; i += 128) dst[i] = src[i];
    }
    __syncthreads();

    const float* W = Ws[wv];
    float acc[8];
#pragma unroll
    for (int r = 0; r < 8; ++r) acc[r] = 0.f;
    for (int k = 0; k < IN_F; ++k) {
        float w = W[k * OUT_F + lane];
#pragma unroll
        for (int r = 0; r < 8; ++r) acc[r] += hs[r][k] * w;
    }

    if (wv == 0) {
        float al = attn_l[lane], ar = attn_r[lane];
        for (int r = 0; r < nr; ++r) {
            feat[(size_t)(row0 + r) * OUT_F + lane] = acc[r];
            float pl = acc[r] * al, pr = acc[r] * ar;
#pragma unroll
            for (int off = 32; off; off >>= 1) {
                pl += __shfl_down(pl, off);
                pr += __shfl_down(pr, off);
            }
            if (lane == 0) { el[row0 + r] = pl; er[row0 + r] = pr; }
        }
    } else {
        for (int r = 0; r < nr; ++r)
            support[(size_t)(row0 + r) * OUT_F + lane] = acc[r];
    }
}

// ---------- edge pass 1: e = leaky(el[src]+er[dst]); atomicMax m[dst] ----------
// order-preserving uint encoding: nonneg -> bits|0x80000000, neg -> ~bits
__global__ __launch_bounds__(256) void k_edge_max(const int* __restrict__ src0,
                                                  const int* __restrict__ dst0,
                                                  const float* __restrict__ el,
                                                  const float* __restrict__ er,
                                                  float* __restrict__ ebuf,
                                                  unsigned* __restrict__ m_enc, int E_) {
    int e = blockIdx.x * blockDim.x + threadIdx.x;
    if (e >= E_) return;
    float v = el[src0[e]] + er[dst0[e]];
    v = v > 0.f ? v : 0.2f * v;
    ebuf[e] = v;
    unsigned u = __float_as_uint(v);
    u = (u & 0x80000000u) ? ~u : (u | 0x80000000u);
    atomicMax(&m_enc[dst0[e]], u);
}

// ---------- edge pass 2: ex = exp(e - m[dst]); atomicAdd s[dst] ----------
__global__ __launch_bounds__(256) void k_edge_exp(const int* __restrict__ dst0,
                                                  const unsigned* __restrict__ m_enc,
                                                  float* __restrict__ ebuf,
                                                  float* __restrict__ sden, int E_) {
    int e = blockIdx.x * blockDim.x + threadIdx.x;
    if (e >= E_) return;
    unsigned u = m_enc[dst0[e]];
    float m = (u & 0x80000000u) ? __uint_as_float(u ^ 0x80000000u)
                                : __uint_as_float(~u);
    float ex = expf(ebuf[e] - m);
    ebuf[e] = ex;
    atomicAdd(&sden[dst0[e]], ex);
}

// ---------- edge scatter: one wave per edge, both branches ----------
// waves [0, E): GAT  out[dst*128 + lane]      += (ex/s[dst]) * feat[src*64+lane]
// waves [E,2E): GC   out[row*128 + 64 + lane] += adj * support[col*64+lane]
__global__ __launch_bounds__(256) void k_scatter(const int* __restrict__ src0,
                                                 const int* __restrict__ dst0,
                                                 const int* __restrict__ row2,
                                                 const int* __restrict__ col2,
                                                 const float* __restrict__ adj_val,
                                                 const float* __restrict__ feat,
                                                 const float* __restrict__ support,
                                                 const float* __restrict__ ebuf,
                                                 const float* __restrict__ sden,
                                                 float* __restrict__ out, int E_) {
    long long gw = ((long long)blockIdx.x * blockDim.x + threadIdx.x) >> 6;
    int lane = threadIdx.x & 63;
    if (gw < E_) {
        int e = (int)gw;
        int s_ = src0[e], d_ = dst0[e];
        float alpha = ebuf[e] / sden[d_];
        float v = alpha * feat[(size_t)s_ * OUT_F + lane];
        atomicAdd(&out[(size_t)d_ * 128 + lane], v);
    } else if (gw < 2LL * E_) {
        int e = (int)(gw - E_);
        int r = row2[e], c = col2[e];
        float v = adj_val[e] * support[(size_t)c * OUT_F + lane];
        atomicAdd(&out[(size_t)r * 128 + OUT_F + lane], v);
    }
}

// ---------- finalize: bias + elu ----------
__global__ __launch_bounds__(256) void k_final(float* __restrict__ out,
                                               const float* __restrict__ bias_gat,
                                               const float* __restrict__ bias_gc, int n) {
    int tid = blockIdx.x * blockDim.x + threadIdx.x;
    if (tid >= n * 128) return;
    int col = tid & 127;
    float b = col < OUT_F ? bias_gat[col] : bias_gc[col - OUT_F];
    float v = out[tid] + b;
    out[tid] = v > 0.f ? v : expm1f(v);
}

extern "C" void kernel_launch(void* const* d_in, const int* in_sizes, int n_in,
                              void* d_out, int out_size, void* d_ws, size_t ws_size,
                              hipStream_t stream) {
    const float* h        = (const float*)d_in[0];
    const int*   src0     = (const int*)d_in[1];
    const int*   dst0     = (const int*)d_in[2];
    const int*   row2     = (const int*)d_in[3];
    const int*   col2     = (const int*)d_in[4];
    const float* adj_val  = (const float*)d_in[5];
    const float* Wg       = (const float*)d_in[6];
    const float* attn_l   = (const float*)d_in[7];
    const float* attn_r   = (const float*)d_in[8];
    const float* bias_gat = (const float*)d_in[9];
    const float* Wc       = (const float*)d_in[10];
    const float* bias_gc  = (const float*)d_in[11];

    int n  = in_sizes[0] / IN_F;
    int E_ = in_sizes[1];
    float* out = (float*)d_out;

    // workspace layout (floats): feat[n*64] support[n*64] el[n] er[n] m_enc[n] sden[n] ebuf[E]
    float*    feat    = (float*)d_ws;
    float*    support = feat + (size_t)n * OUT_F;
    float*    el      = support + (size_t)n * OUT_F;
    float*    er      = el + n;
    unsigned* m_enc   = (unsigned*)(er + n);
    float*    sden    = (float*)(m_enc + n);
    float*    ebuf    = sden + n;

    k_init<<<(n * 32 + 255) / 256, 256, 0, stream>>>(out, m_enc, sden, n);
    k_gemm<<<(n + 7) / 8, 128, 0, stream>>>(h, Wg, Wc, attn_l, attn_r,
                                            feat, support, el, er, n);
    k_edge_max<<<(E_ + 255) / 256, 256, 0, stream>>>(src0, dst0, el, er, ebuf, m_enc, E_);
    k_edge_exp<<<(E_ + 255) / 256, 256, 0, stream>>>(dst0, m_enc, ebuf, sden, E_);
    long long scatter_threads = 2LL * E_ * 64;
    k_scatter<<<(int)((scatter_threads + 255) / 256), 256, 0, stream>>>(
        src0, dst0, row2, col2, adj_val, feat, support, ebuf, sden, out, E_);
    k_final<<<(n * 128 + 255) / 256, 256, 0, stream>>>(out, bias_gat, bias_gc, n);
}

// Round 2
// 432.750 us; speedup vs baseline: 1.3820x; 1.3820x over previous
//
#include <hip/hip_runtime.h>
#include <hip/hip_bf16.h>
#include <math.h>

#define IN_F 128
#define OUT_F 64

// ===================== shared: dual GEMM =====================
// block = 256 threads (4 waves). waves 0,1 -> GAT rows [0..8),[8..16);
// waves 2,3 -> GC rows [0..8),[8..16). 16 rows/block.
__global__ __launch_bounds__(256) void k_gemm(const float* __restrict__ h,
                                              const float* __restrict__ Wg,
                                              const float* __restrict__ Wc,
                                              const float* __restrict__ attn_l,
                                              const float* __restrict__ attn_r,
                                              float* __restrict__ feat,
                                              float* __restrict__ support,
                                              float* __restrict__ el,
                                              float* __restrict__ er, int n) {
    __shared__ float Ws[2][IN_F * OUT_F];   // 64 KB
    __shared__ float hs[16][IN_F];          // 8 KB
    for (int i = threadIdx.x; i < IN_F * OUT_F; i += 256) {
        Ws[0][i] = Wg[i];
        Ws[1][i] = Wc[i];
    }
    int row0 = blockIdx.x * 16;
    int nr = min(16, n - row0);
    {
        const float4* src = (const float4*)(h + (size_t)row0 * IN_F);
        float4* dst = (float4*)hs;
        int tot = nr * (IN_F / 4);
        for (int i = threadIdx.x; i < tot; i += 256) dst[i] = src[i];
    }
    __syncthreads();

    int lane = threadIdx.x & 63;
    int wv = threadIdx.x >> 6;   // 0..3
    int mat = wv >> 1;           // 0 = GAT, 1 = GC
    int rbase = (wv & 1) * 8;

    const float* W = Ws[mat];
    float acc[8];
#pragma unroll
    for (int r = 0; r < 8; ++r) acc[r] = 0.f;
    for (int k = 0; k < IN_F; ++k) {
        float w = W[k * OUT_F + lane];
#pragma unroll
        for (int r = 0; r < 8; ++r) acc[r] += hs[rbase + r][k] * w;
    }

    if (mat == 0) {
        float al = attn_l[lane], ar = attn_r[lane];
        for (int r = 0; r < 8; ++r) {
            int row = row0 + rbase + r;
            if (row >= n) break;
            feat[(size_t)row * OUT_F + lane] = acc[r];
            float pl = acc[r] * al, pr = acc[r] * ar;
#pragma unroll
            for (int off = 32; off; off >>= 1) {
                pl += __shfl_down(pl, off);
                pr += __shfl_down(pr, off);
            }
            if (lane == 0) { el[row] = pl; er[row] = pr; }
        }
    } else {
        for (int r = 0; r < 8; ++r) {
            int row = row0 + rbase + r;
            if (row >= n) break;
            support[(size_t)row * OUT_F + lane] = acc[r];
        }
    }
}

// ===================== CSR build =====================
__global__ __launch_bounds__(256) void k_zero_cnt(int* __restrict__ cnt, int tot) {
    int g = blockIdx.x * blockDim.x + threadIdx.x;
    if (g < tot) cnt[g] = 0;
}

__global__ __launch_bounds__(256) void k_hist(const int* __restrict__ dst0,
                                              const int* __restrict__ row2,
                                              int* __restrict__ cnt, int n, int E_) {
    int e = blockIdx.x * blockDim.x + threadIdx.x;
    if (e >= E_) return;
    atomicAdd(&cnt[dst0[e]], 1);
    atomicAdd(&cnt[n + row2[e]], 1);
}

// scan stage 1: per-block (1024 elems) exclusive scan + block totals
__global__ __launch_bounds__(256) void k_scan1(const int* __restrict__ cnt,
                                               int* __restrict__ offs,
                                               int* __restrict__ bsum, int tot) {
    __shared__ int sh[256];
    int t = threadIdx.x;
    int g0 = blockIdx.x * 1024 + t * 4;
    int v[4];
#pragma unroll
    for (int i = 0; i < 4; ++i) {
        int g = g0 + i;
        v[i] = (g < tot) ? cnt[g] : 0;
    }
    int tsum = v[0] + v[1] + v[2] + v[3];
    sh[t] = tsum;
    __syncthreads();
    for (int off = 1; off < 256; off <<= 1) {
        int x = (t >= off) ? sh[t - off] : 0;
        __syncthreads();
        sh[t] += x;
        __syncthreads();
    }
    int run = sh[t] - tsum;  // exclusive base for this thread
#pragma unroll
    for (int i = 0; i < 4; ++i) {
        int g = g0 + i;
        if (g < tot) offs[g] = run;
        run += v[i];
    }
    if (t == 255) bsum[blockIdx.x] = sh[255];
}

// scan stage 2: single block scans block totals (exclusive, in place) + sentinel
__global__ __launch_bounds__(256) void k_scan2(int* __restrict__ bsum, int nb,
                                               int* __restrict__ offs, int tot,
                                               int grand) {
    __shared__ int sh[256];
    int t = threadIdx.x;
    int carry = 0;
    for (int base = 0; base < nb; base += 256) {
        int idx = base + t;
        int v = (idx < nb) ? bsum[idx] : 0;
        __syncthreads();
        sh[t] = v;
        __syncthreads();
        for (int off = 1; off < 256; off <<= 1) {
            int x = (t >= off) ? sh[t - off] : 0;
            __syncthreads();
            sh[t] += x;
            __syncthreads();
        }
        if (idx < nb) bsum[idx] = sh[t] - v + carry;
        carry += sh[255];
    }
    if (t == 0) offs[tot] = grand;  // sentinel
}

// scan stage 3: add block bases
__global__ __launch_bounds__(256) void k_scan3(int* __restrict__ offs,
                                               const int* __restrict__ bsum, int tot) {
    int g = blockIdx.x * blockDim.x + threadIdx.x;
    if (g < tot) offs[g] += bsum[g >> 10];
}

// bucket fill: GAT slot <- src ; GC slot <- edge id. cnt used as countdown.
__global__ __launch_bounds__(256) void k_fill(const int* __restrict__ src0,
                                              const int* __restrict__ dst0,
                                              const int* __restrict__ row2,
                                              const int* __restrict__ offs,
                                              int* __restrict__ cnt,
                                              int* __restrict__ bkt, int n, int E_) {
    int e = blockIdx.x * blockDim.x + threadIdx.x;
    if (e >= E_) return;
    int d = dst0[e];
    int pos = offs[d] + atomicSub(&cnt[d], 1) - 1;
    bkt[pos] = src0[e];
    int r = row2[e];
    int pos2 = offs[n + r] + atomicSub(&cnt[n + r], 1) - 1;
    bkt[pos2] = e;
}

// ===================== aggregation: one wave per node =====================
__global__ __launch_bounds__(256) void k_agg_gat(const int* __restrict__ bkt,
                                                 const int* __restrict__ offs,
                                                 const float* __restrict__ el,
                                                 const float* __restrict__ er,
                                                 const float* __restrict__ feat,
                                                 const float* __restrict__ bias,
                                                 float* __restrict__ out, int n) {
    int wid = (int)(((long long)blockIdx.x * blockDim.x + threadIdx.x) >> 6);
    int lane = threadIdx.x & 63;
    if (wid >= n) return;
    int start = offs[wid], end = offs[wid + 1];
    float erd = er[wid];
    // pass 1: max over this node's edges (lanes strided)
    float mx = -3.4e38f;
    for (int j = start + lane; j < end; j += 64) {
        int s = bkt[j];
        float v = el[s] + erd;
        v = v > 0.f ? v : 0.2f * v;
        mx = fmaxf(mx, v);
    }
#pragma unroll
    for (int off = 32; off; off >>= 1) mx = fmaxf(mx, __shfl_xor(mx, off));
    // pass 2: exp-weighted accumulate
    float acc = 0.f, sw = 0.f;
    for (int j = start; j < end; ++j) {
        int s = bkt[j];
        float v = el[s] + erd;
        v = v > 0.f ? v : 0.2f * v;
        float w = expf(v - mx);
        sw += w;
        acc += w * feat[(size_t)s * OUT_F + lane];
    }
    float inv = (end > start) ? 1.f / sw : 0.f;
    float z = acc * inv + bias[lane];
    out[(size_t)wid * 128 + lane] = z > 0.f ? z : expm1f(z);
}

__global__ __launch_bounds__(256) void k_agg_gc(const int* __restrict__ bkt,
                                                const int* __restrict__ offs,
                                                const int* __restrict__ col2,
                                                const float* __restrict__ adj_val,
                                                const float* __restrict__ support,
                                                const float* __restrict__ bias,
                                                float* __restrict__ out, int n) {
    int wid = (int)(((long long)blockIdx.x * blockDim.x + threadIdx.x) >> 6);
    int lane = threadIdx.x & 63;
    if (wid >= n) return;
    int start = offs[n + wid], end = offs[n + wid + 1];
    float acc = 0.f;
    for (int j = start; j < end; ++j) {
        int eid = bkt[j];
        float a = adj_val[eid];
        int c = col2[eid];
        acc += a * support[(size_t)c * OUT_F + lane];
    }
    float z = acc + bias[lane];
    out[(size_t)wid * 128 + OUT_F + lane] = z > 0.f ? z : expm1f(z);
}

// ===================== fallback path (round-1, proven) =====================
__global__ __launch_bounds__(256) void k_init(float* __restrict__ out,
                                              unsigned* __restrict__ m_enc,
                                              float* __restrict__ sden, int n) {
    int tid = blockIdx.x * blockDim.x + threadIdx.x;
    int tot4 = n * 32;
    if (tid < tot4) ((float4*)out)[tid] = make_float4(0.f, 0.f, 0.f, 0.f);
    if (tid < n) { m_enc[tid] = 0u; sden[tid] = 0.f; }
}

__global__ __launch_bounds__(256) void k_edge_max(const int* __restrict__ src0,
                                                  const int* __restrict__ dst0,
                                                  const float* __restrict__ el,
                                                  const float* __restrict__ er,
                                                  float* __restrict__ ebuf,
                                                  unsigned* __restrict__ m_enc, int E_) {
    int e = blockIdx.x * blockDim.x + threadIdx.x;
    if (e >= E_) return;
    float v = el[src0[e]] + er[dst0[e]];
    v = v > 0.f ? v : 0.2f * v;
    ebuf[e] = v;
    unsigned u = __float_as_uint(v);
    u = (u & 0x80000000u) ? ~u : (u | 0x80000000u);
    atomicMax(&m_enc[dst0[e]], u);
}

__global__ __launch_bounds__(256) void k_edge_exp(const int* __restrict__ dst0,
                                                  const unsigned* __restrict__ m_enc,
                                                  float* __restrict__ ebuf,
                                                  float* __restrict__ sden, int E_) {
    int e = blockIdx.x * blockDim.x + threadIdx.x;
    if (e >= E_) return;
    unsigned u = m_enc[dst0[e]];
    float m = (u & 0x80000000u) ? __uint_as_float(u ^ 0x80000000u)
                                : __uint_as_float(~u);
    float ex = expf(ebuf[e] - m);
    ebuf[e] = ex;
    atomicAdd(&sden[dst0[e]], ex);
}

__global__ __launch_bounds__(256) void k_scatter(const int* __restrict__ src0,
                                                 const int* __restrict__ dst0,
                                                 const int* __restrict__ row2,
                                                 const int* __restrict__ col2,
                                                 const float* __restrict__ adj_val,
                                                 const float* __restrict__ feat,
                                                 const float* __restrict__ support,
                                                 const float* __restrict__ ebuf,
                                                 const float* __restrict__ sden,
                                                 float* __restrict__ out, int E_) {
    long long gw = ((long long)blockIdx.x * blockDim.x + threadIdx.x) >> 6;
    int lane = threadIdx.x & 63;
    if (gw < E_) {
        int e = (int)gw;
        int s_ = src0[e], d_ = dst0[e];
        float alpha = ebuf[e] / sden[d_];
        float v = alpha * feat[(size_t)s_ * OUT_F + lane];
        atomicAdd(&out[(size_t)d_ * 128 + lane], v);
    } else if (gw < 2LL * E_) {
        int e = (int)(gw - E_);
        int r = row2[e], c = col2[e];
        float v = adj_val[e] * support[(size_t)c * OUT_F + lane];
        atomicAdd(&out[(size_t)r * 128 + OUT_F + lane], v);
    }
}

__global__ __launch_bounds__(256) void k_final(float* __restrict__ out,
                                               const float* __restrict__ bias_gat,
                                               const float* __restrict__ bias_gc, int n) {
    int tid = blockIdx.x * blockDim.x + threadIdx.x;
    if (tid >= n * 128) return;
    int col = tid & 127;
    float b = col < OUT_F ? bias_gat[col] : bias_gc[col - OUT_F];
    float v = out[tid] + b;
    out[tid] = v > 0.f ? v : expm1f(v);
}

// ===================== launch =====================
extern "C" void kernel_launch(void* const* d_in, const int* in_sizes, int n_in,
                              void* d_out, int out_size, void* d_ws, size_t ws_size,
                              hipStream_t stream) {
    const float* h        = (const float*)d_in[0];
    const int*   src0     = (const int*)d_in[1];
    const int*   dst0     = (const int*)d_in[2];
    const int*   row2     = (const int*)d_in[3];
    const int*   col2     = (const int*)d_in[4];
    const float* adj_val  = (const float*)d_in[5];
    const float* Wg       = (const float*)d_in[6];
    const float* attn_l   = (const float*)d_in[7];
    const float* attn_r   = (const float*)d_in[8];
    const float* bias_gat = (const float*)d_in[9];
    const float* Wc       = (const float*)d_in[10];
    const float* bias_gc  = (const float*)d_in[11];

    int n  = in_sizes[0] / IN_F;
    int E_ = in_sizes[1];
    float* out = (float*)d_out;

    size_t nf = (size_t)n * OUT_F;
    float* feat    = (float*)d_ws;
    float* support = feat + nf;
    float* el      = support + nf;
    float* er      = el + n;

    int tot = 2 * n;
    int nblk = (tot + 1023) / 1024;

    // new-path layout after er
    int* cnt  = (int*)(er + n);
    int* offs = cnt + tot;            // tot+1 entries (sentinel)
    int* bkt  = offs + (tot + 1);     // 2E entries
    int* bsum = bkt + 2 * (size_t)E_; // nblk entries
    size_t need = (size_t)((char*)(bsum + nblk) - (char*)d_ws);

    // shared: dual GEMM
    k_gemm<<<(n + 15) / 16, 256, 0, stream>>>(h, Wg, Wc, attn_l, attn_r,
                                              feat, support, el, er, n);

    if (ws_size >= need) {
        // ---- CSR path ----
        k_zero_cnt<<<(tot + 255) / 256, 256, 0, stream>>>(cnt, tot);
        k_hist<<<(E_ + 255) / 256, 256, 0, stream>>>(dst0, row2, cnt, n, E_);
        k_scan1<<<nblk, 256, 0, stream>>>(cnt, offs, bsum, tot);
        k_scan2<<<1, 256, 0, stream>>>(bsum, nblk, offs, tot, 2 * E_);
        k_scan3<<<(tot + 255) / 256, 256, 0, stream>>>(offs, bsum, tot);
        k_fill<<<(E_ + 255) / 256, 256, 0, stream>>>(src0, dst0, row2, offs, cnt, bkt, n, E_);
        int aggblocks = (n * 64 + 255) / 256;
        k_agg_gat<<<aggblocks, 256, 0, stream>>>(bkt, offs, el, er, feat, bias_gat, out, n);
        k_agg_gc<<<aggblocks, 256, 0, stream>>>(bkt, offs, col2, adj_val, support, bias_gc, out, n);
    } else {
        // ---- fallback: proven atomic path ----
        unsigned* m_enc = (unsigned*)(er + n);
        float*    sden  = (float*)(m_enc + n);
        float*    ebuf  = sden + n;
        k_init<<<(n * 32 + 255) / 256, 256, 0, stream>>>(out, m_enc, sden, n);
        k_edge_max<<<(E_ + 255) / 256, 256, 0, stream>>>(src0, dst0, el, er, ebuf, m_enc, E_);
        k_edge_exp<<<(E_ + 255) / 256, 256, 0, stream>>>(dst0, m_enc, ebuf, sden, E_);
        long long scatter_threads = 2LL * E_ * 64;
        k_scatter<<<(int)((scatter_threads + 255) / 256), 256, 0, stream>>>(
            src0, dst0, row2, col2, adj_val, feat, support, ebuf, sden, out, E_);
        k_final<<<(n * 128 + 255) / 256, 256, 0, stream>>>(out, bias_gat, bias_gc, n);
    }
}